// Round 18
// baseline (1991.654 us; speedup 1.0000x reference)
//
#include <hip/hip_runtime.h>
#include <hip/hip_bf16.h>
#include <hip/hip_cooperative_groups.h>

// TAGConv x2 GNN on MI355X. v18:
//  - fuse1 REVERTED to 3 gemmn kernels (fuse1's 60-tile serial chain @2
//    blocks/CU measured 104us vs ~60 for the split chain). fuse2 kept.
//  - props merged into cooperative kernels (prop6 / horner6) with
//    grid.sync() between hops: removes 10 kernel-boundary drains + keeps
//    esrc/off warm in L2. 1024 blocks (co-residency-safe at 4 blocks/CU).
//  - rest = v16: gemmc BM=128 concat GEMM, gemmn (A staged once),
//    single-pass fill_edges, 2-stage trows reduce.

#define EPS_MSG 1e-7f
#define BNSCALE 0.9999950000374997f  // 1/sqrt(1+1e-5)
#define LO_INV 0.0009765625f         // 2^-10

typedef _Float16 half_t;
typedef _Float16 f16x8 __attribute__((ext_vector_type(8)));
typedef float f32x4 __attribute__((ext_vector_type(4)));

namespace cg = cooperative_groups;

__device__ __forceinline__ void gld16(const char* g, char* l) {
    __builtin_amdgcn_global_load_lds(
        (const __attribute__((address_space(1))) void*)g,
        (__attribute__((address_space(3))) void*)l, 16, 0, 0);
}

__device__ __forceinline__ float hlo(unsigned p) {
    unsigned short u = (unsigned short)(p & 0xffffu);
    half_t h;
    __builtin_memcpy(&h, &u, 2);
    return (float)h;
}
__device__ __forceinline__ float hhi(unsigned p) {
    unsigned short u = (unsigned short)(p >> 16);
    half_t h;
    __builtin_memcpy(&h, &u, 2);
    return (float)h;
}
__device__ __forceinline__ unsigned fpack2(float x, float y) {
    half_t a = (half_t)x, b = (half_t)y;
    unsigned short ua, ub;
    __builtin_memcpy(&ua, &a, 2);
    __builtin_memcpy(&ub, &b, 2);
    return (unsigned)ua | ((unsigned)ub << 16);
}

__device__ __forceinline__ float epi_apply(float v, int gc, int epi,
                                           const float* __restrict__ bias,
                                           const float* __restrict__ bng,
                                           const float* __restrict__ bnb) {
    if (epi == 1) {
        v += bias[gc];
    } else if (epi == 2) {
        v = bng[gc] * ((v + bias[gc]) * BNSCALE) + bnb[gc];
        v = fmaxf(v, 0.f);
    } else if (epi == 3) {
        v = fmaxf(v + bias[gc], 0.f);
    }
    return v;
}

// ---------------- CSR build ----------------

__global__ void zero2_i32(int* __restrict__ a, int* __restrict__ b, int n) {
    int i = blockIdx.x * blockDim.x + threadIdx.x;
    if (i < n) {
        a[i] = 0;
        b[i] = 0;
    }
}

__global__ void count_deg(const int* __restrict__ col, int* __restrict__ deg, int E) {
    int e = blockIdx.x * blockDim.x + threadIdx.x;
    if (e < E) atomicAdd(&deg[col[e]], 1);
}

__global__ void compute_dis_s(const int* __restrict__ deg, float* __restrict__ dis,
                              float* __restrict__ s, float* __restrict__ rs, int N) {
    int v = blockIdx.x * blockDim.x + threadIdx.x;
    if (v >= N) return;
    int d = deg[v];
    float di = (d > 0) ? rsqrtf((float)d) : 0.f;
    dis[v] = di;
    s[v] = (d > 0) ? di : 1.f;
    rs[v] = (d > 0) ? sqrtf((float)d) : 1.f;
}

__global__ void scan_blk(const int* __restrict__ deg, int* __restrict__ off,
                         int* __restrict__ bsum, int N) {
    __shared__ int sm[1024];
    int i = blockIdx.x * 1024 + threadIdx.x;
    sm[threadIdx.x] = (i < N) ? deg[i] : 0;
    __syncthreads();
    for (int ofs = 1; ofs < 1024; ofs <<= 1) {
        int t = (threadIdx.x >= (unsigned)ofs) ? sm[threadIdx.x - ofs] : 0;
        __syncthreads();
        sm[threadIdx.x] += t;
        __syncthreads();
    }
    if (i < N) off[i + 1] = sm[threadIdx.x];
    if (threadIdx.x == 0) bsum[blockIdx.x] = sm[1023];
}

__global__ void scan_top(int* __restrict__ bsum, int nb) {
    if (threadIdx.x == 0 && blockIdx.x == 0) {
        int a = 0;
        for (int b = 0; b < nb; ++b) {
            int t = bsum[b];
            bsum[b] = a;
            a += t;
        }
    }
}

__global__ void scan_add(int* __restrict__ off, const int* __restrict__ bsum, int N) {
    int i = blockIdx.x * 1024 + threadIdx.x;
    if (i < N) off[i + 1] += bsum[blockIdx.x];
    if (i == 0) off[0] = 0;
}

__global__ void fill_edges(const int* __restrict__ row, const int* __restrict__ col,
                           const int* __restrict__ off, int* __restrict__ cur,
                           unsigned short* __restrict__ esrc, int E) {
    int e = blockIdx.x * blockDim.x + threadIdx.x;
    if (e >= E) return;
    int c = col[e];
    int pos = off[c] + atomicAdd(&cur[c], 1);
    esrc[pos] = (unsigned short)row[e];
}

// ---------------- conversions ----------------

__global__ void conv_xg(const float* __restrict__ x, half_t* __restrict__ slab,
                        half_t* __restrict__ g0, const float* __restrict__ dis,
                        const float* __restrict__ s, int total) {
    int i = blockIdx.x * blockDim.x + threadIdx.x;
    if (i >= total) return;
    int v = i >> 7, c = i & 127;
    float xv = x[i];
    slab[(size_t)v * 896 + c] = (half_t)(s[v] * xv);
    g0[i] = (half_t)(dis[v] * fmaxf(xv, 0.f));
}

__device__ __forceinline__ void wcv(const float* __restrict__ in, half_t* __restrict__ oh,
                                    half_t* __restrict__ ol, int nm, int K, int Nn, int i) {
    int KT = nm * K;
    int n = i / KT;
    int rem = i - n * KT;
    int km = rem / K, k = rem - km * K;
    float w = in[(size_t)km * K * Nn + (size_t)k * Nn + n];
    half_t h = (half_t)w;
    oh[i] = h;
    ol[i] = (half_t)((w - (float)h) * 1024.f);
}

__global__ void conv_all(const float* l1, const float* l2, const float* a1, const float* b1,
                         const float* a2, const float* b2, half_t* W1h, half_t* W1l,
                         half_t* W2h, half_t* W2l, half_t* M1ah, half_t* M1al, half_t* M1bh,
                         half_t* M1bl, half_t* M2ah, half_t* M2al, half_t* M2bh,
                         half_t* M2bl) {
    int i = blockIdx.x * blockDim.x + threadIdx.x;
    if (i < 114688) {
        wcv(l1, W1h, W1l, 7, 128, 128, i);  // concat-K layout for layer-1
    } else if (i < 172032) {
        // W2: concat-N layout. B^T[np][k], np = km*64+n, value = l2[km][k][n]
        int j = i - 114688;
        int np = j >> 7, k = j & 127;
        int km = np >> 6, n = np & 63;
        float w = l2[(size_t)km * 128 * 64 + (size_t)k * 64 + n];
        half_t h = (half_t)w;
        W2h[j] = h;
        W2l[j] = (half_t)((w - (float)h) * 1024.f);
    } else if (i < 204800) {
        wcv(a1, M1ah, M1al, 1, 128, 256, i - 172032);
    } else if (i < 237568) {
        wcv(b1, M1bh, M1bl, 1, 256, 128, i - 204800);
    } else if (i < 245760) {
        wcv(a2, M2ah, M2al, 1, 64, 128, i - 237568);
    } else if (i < 253952) {
        wcv(b2, M2bh, M2bl, 1, 128, 64, i - 245760);
    }
}

__global__ void trows_part(const float* __restrict__ l2, float* __restrict__ partial) {
    __shared__ float sm[256];
    int k = blockIdx.x / 8 + 1;
    int p = blockIdx.x % 8;
    int c = threadIdx.x & 63;
    int q = threadIdx.x >> 6;
    float a = 0.f;
    int kk0 = p * 16 + q * 4;
#pragma unroll
    for (int t = 0; t < 4; ++t)
        a += l2[(size_t)k * 128 * 64 + (kk0 + t) * 64 + c];
    sm[threadIdx.x] = a;
    __syncthreads();
    if (q == 0)
        partial[(size_t)blockIdx.x * 64 + c] =
            (sm[c] + sm[64 + c]) + (sm[128 + c] + sm[192 + c]);
}

__global__ void trows_final(const float* __restrict__ partial, float* __restrict__ T) {
    int j = threadIdx.x >> 6;
    int c = threadIdx.x & 63;
    if (j >= 6) return;
    float a = 0.f;
    for (int k = j + 1; k <= 6; ++k)
#pragma unroll
        for (int p = 0; p < 8; ++p) a += partial[(size_t)((k - 1) * 8 + p) * 64 + c];
    T[j * 64 + c] = a;
}

// ---------------- propagation bodies ----------------

__device__ __forceinline__ void prop_hop(const unsigned* __restrict__ gin, int idl,
                                         unsigned* __restrict__ gout, int odl,
                                         const float* __restrict__ dis,
                                         const int* __restrict__ off,
                                         const unsigned short* __restrict__ esrc, int N) {
    const int lane = threadIdx.x & 63;
    const int w = threadIdx.x >> 6;
    const int stride = gridDim.x * 4;
    for (int v = blockIdx.x * 4 + w; v < N; v += stride) {
        int s = off[v], e = off[v + 1];
        float2 A0 = {0.f, 0.f}, A1 = {0.f, 0.f}, A2 = {0.f, 0.f}, A3 = {0.f, 0.f};
        float2 A4 = {0.f, 0.f}, A5 = {0.f, 0.f}, A6 = {0.f, 0.f}, A7 = {0.f, 0.f};
        for (int i = s; i < e; i += 8) {
            unsigned p[8];
            int ok[8];
#pragma unroll
            for (int j = 0; j < 8; ++j) {
                int ij = i + j;
                ok[j] = ij < e;
                int idx = ok[j] ? ij : e - 1;
                p[j] = gin[esrc[idx] * idl + lane];
            }
            A0.x += ok[0] ? hlo(p[0]) : 0.f; A0.y += ok[0] ? hhi(p[0]) : 0.f;
            A1.x += ok[1] ? hlo(p[1]) : 0.f; A1.y += ok[1] ? hhi(p[1]) : 0.f;
            A2.x += ok[2] ? hlo(p[2]) : 0.f; A2.y += ok[2] ? hhi(p[2]) : 0.f;
            A3.x += ok[3] ? hlo(p[3]) : 0.f; A3.y += ok[3] ? hhi(p[3]) : 0.f;
            A4.x += ok[4] ? hlo(p[4]) : 0.f; A4.y += ok[4] ? hhi(p[4]) : 0.f;
            A5.x += ok[5] ? hlo(p[5]) : 0.f; A5.y += ok[5] ? hhi(p[5]) : 0.f;
            A6.x += ok[6] ? hlo(p[6]) : 0.f; A6.y += ok[6] ? hhi(p[6]) : 0.f;
            A7.x += ok[7] ? hlo(p[7]) : 0.f; A7.y += ok[7] ? hhi(p[7]) : 0.f;
        }
        float ax = ((A0.x + A1.x) + (A2.x + A3.x)) + ((A4.x + A5.x) + (A6.x + A7.x));
        float ay = ((A0.y + A1.y) + (A2.y + A3.y)) + ((A4.y + A5.y) + (A6.y + A7.y));
        float dv = dis[v];
        float ce = (float)(e - s) * EPS_MSG;
        float hx = fmaf(dv, ax, ce);
        float hy = fmaf(dv, ay, ce);
        gout[v * odl + lane] = fpack2(dv * hx, dv * hy);
    }
}

__global__ void __launch_bounds__(256) prop6(const unsigned* __restrict__ g0U,
                                             unsigned* __restrict__ slabU,
                                             const float* __restrict__ dis,
                                             const int* __restrict__ off,
                                             const unsigned short* __restrict__ esrc, int N) {
    cg::grid_group grid = cg::this_grid();
    prop_hop(g0U, 64, slabU + 64, 448, dis, off, esrc, N);
    for (int k = 2; k <= 6; ++k) {
        grid.sync();
        prop_hop(slabU + (size_t)(k - 1) * 64, 448, slabU + (size_t)k * 64, 448, dis, off,
                 esrc, N);
    }
}

__device__ __forceinline__ void horner_step(const half_t* __restrict__ uin, int ldu,
                                            const half_t* __restrict__ pj,
                                            half_t* __restrict__ uout,
                                            const float* __restrict__ dis,
                                            const int* __restrict__ off,
                                            const unsigned short* __restrict__ esrc,
                                            const float* __restrict__ tj,
                                            const float* __restrict__ bias2, int finalStep,
                                            int N) {
    const int c = threadIdx.x & 63;
    const int w = threadIdx.x >> 6;
    const int stride = gridDim.x * 4;
    for (int v = blockIdx.x * 4 + w; v < N; v += stride) {
        int s = off[v], e = off[v + 1];
        float a0 = 0.f, a1 = 0.f, a2 = 0.f, a3 = 0.f;
        float a4 = 0.f, a5 = 0.f, a6 = 0.f, a7 = 0.f;
        for (int i = s; i < e; i += 8) {
            float q[8];
            int ok[8];
#pragma unroll
            for (int j = 0; j < 8; ++j) {
                int ij = i + j;
                ok[j] = ij < e;
                int idx = ok[j] ? ij : e - 1;
                q[j] = (float)uin[(size_t)esrc[idx] * ldu + c];
            }
            a0 += ok[0] ? q[0] : 0.f;
            a1 += ok[1] ? q[1] : 0.f;
            a2 += ok[2] ? q[2] : 0.f;
            a3 += ok[3] ? q[3] : 0.f;
            a4 += ok[4] ? q[4] : 0.f;
            a5 += ok[5] ? q[5] : 0.f;
            a6 += ok[6] ? q[6] : 0.f;
            a7 += ok[7] ? q[7] : 0.f;
        }
        float acc = ((a0 + a1) + (a2 + a3)) + ((a4 + a5) + (a6 + a7));
        float dv = dis[v];
        float base = (float)pj[(size_t)v * 448 + c] + (float)(e - s) * EPS_MSG * tj[c];
        float u = fmaf(dv, acc, base);
        if (finalStep)
            uout[(size_t)v * 64 + c] = (half_t)(u + bias2[c]);
        else
            uout[(size_t)v * 64 + c] = (half_t)(dv * u);
    }
}

__global__ void __launch_bounds__(256) horner6(const half_t* __restrict__ slab,
                                               half_t* __restrict__ ub0,
                                               half_t* __restrict__ ub1,
                                               half_t* __restrict__ ACC2,
                                               const float* __restrict__ dis,
                                               const int* __restrict__ off,
                                               const unsigned short* __restrict__ esrc,
                                               const float* __restrict__ Trow,
                                               const float* __restrict__ bias2, int N) {
    cg::grid_group grid = cg::this_grid();
    horner_step(slab + 384, 448, slab + 320, ub0, dis, off, esrc, Trow + 5 * 64, nullptr, 0, N);
    grid.sync();
    horner_step(ub0, 64, slab + 256, ub1, dis, off, esrc, Trow + 4 * 64, nullptr, 0, N);
    grid.sync();
    horner_step(ub1, 64, slab + 192, ub0, dis, off, esrc, Trow + 3 * 64, nullptr, 0, N);
    grid.sync();
    horner_step(ub0, 64, slab + 128, ub1, dis, off, esrc, Trow + 2 * 64, nullptr, 0, N);
    grid.sync();
    horner_step(ub1, 64, slab + 64, ub0, dis, off, esrc, Trow + 1 * 64, nullptr, 0, N);
    grid.sync();
    horner_step(ub0, 64, slab, ACC2, dis, off, esrc, Trow, bias2, 1, N);
}

// ---------------- concat GEMM: BM=128, BN=128, BK=32, 512 thr, dbuf ---------

__global__ __launch_bounds__(512) void gemmc(
    int M, int kiters, const half_t* __restrict__ A, int lda,
    const half_t* __restrict__ Bhp, const half_t* __restrict__ Blp, int ldb,
    half_t* __restrict__ Cp, int ldc, const float* __restrict__ rs,
    const float* __restrict__ bias) {
    constexpr int ABY = 8192, BBY = 8192, BUFBY = ABY + 2 * BBY;  // 24576
    __shared__ __align__(16) char lds[2][BUFBY];

    const int tid = threadIdx.x, lane = tid & 63, w = tid >> 6;  // 8 waves
    const int wr = w >> 1, wc = w & 1;
    const int m0 = blockIdx.x * 128;
    const int l15 = lane & 15, lq = lane >> 4;
    const int lr = lane >> 2, lc = lane & 3;

    const char* gA = (const char*)A;
    const char* gBh = (const char*)Bhp;
    const char* gBl = (const char*)Blp;
    const size_t ldaB = (size_t)lda * 2, ldbB = (size_t)ldb * 2;

    auto stage = [&](int kt, int buf) {
        const int k0b = kt * 64;
        char* base = lds[0] + buf * BUFBY;
        int r = w * 16 + lr;
        int sc = (lc ^ (r & 3)) << 4;
        {
            int gv = m0 + r;
            if (gv >= M) gv = M - 1;
            gld16(gA + (size_t)gv * ldaB + k0b + sc, base + w * 1024);
        }
        {
            size_t goff = (size_t)r * ldbB + k0b + sc;
            gld16(gBh + goff, base + ABY + w * 1024);
            gld16(gBl + goff, base + ABY + BBY + w * 1024);
        }
    };

    f32x4 acch[2][4], accl[2][4];
#pragma unroll
    for (int fm = 0; fm < 2; ++fm)
#pragma unroll
        for (int fn = 0; fn < 4; ++fn) {
            acch[fm][fn] = (f32x4){0.f, 0.f, 0.f, 0.f};
            accl[fm][fn] = (f32x4){0.f, 0.f, 0.f, 0.f};
        }

    auto compute = [&](int buf) {
        const char* Ab = lds[0] + buf * BUFBY;
        const char* Bhb = Ab + ABY;
        const char* Blb = Ab + ABY + BBY;
        f16x8 af[2];
#pragma unroll
        for (int fm = 0; fm < 2; ++fm) {
            int ra = wr * 32 + fm * 16 + l15;
            af[fm] = *(const f16x8*)(Ab + ra * 64 + ((lq ^ (ra & 3)) << 4));
        }
#pragma unroll
        for (int fn = 0; fn < 4; ++fn) {
            int rb = wc * 64 + fn * 16 + l15;
            int o = rb * 64 + ((lq ^ (rb & 3)) << 4);
            f16x8 bhv = *(const f16x8*)(Bhb + o);
            f16x8 blv = *(const f16x8*)(Blb + o);
#pragma unroll
            for (int fm = 0; fm < 2; ++fm) {
                acch[fm][fn] = __builtin_amdgcn_mfma_f32_16x16x32_f16(af[fm], bhv, acch[fm][fn], 0, 0, 0);
                accl[fm][fn] = __builtin_amdgcn_mfma_f32_16x16x32_f16(af[fm], blv, accl[fm][fn], 0, 0, 0);
            }
        }
    };

    stage(0, 0);
    int buf = 0;
    for (int kt = 0; kt < kiters; ++kt) {
        __syncthreads();
        if (kt + 1 < kiters) stage(kt + 1, buf ^ 1);
        compute(buf);
        buf ^= 1;
    }

#pragma unroll
    for (int fm = 0; fm < 2; ++fm)
#pragma unroll
        for (int fn = 0; fn < 4; ++fn)
#pragma unroll
            for (int i = 0; i < 4; ++i) {
                int gr = m0 + wr * 32 + fm * 16 + lq * 4 + i;
                if (gr >= M) continue;
                int gc = wc * 64 + fn * 16 + l15;
                float v = acch[fm][fn][i] + accl[fm][fn][i] * LO_INV;
                v = v * rs[gr] + bias[gc];
                Cp[(size_t)gr * ldc + gc] = (half_t)v;
            }
}

// ---------------- loop-N GEMM: A staged once, B dbuf per strip-tile ----------

template <int KT, int NS, int OUTF32>
__global__ __launch_bounds__(256) void gemmn(
    int M, const half_t* __restrict__ A, int lda, const half_t* __restrict__ Bhp,
    const half_t* __restrict__ Blp, int ldb, void* __restrict__ Cp, int ldc, int epi,
    const float* __restrict__ bias, const float* __restrict__ bng,
    const float* __restrict__ bnb, const float* __restrict__ scaleRows, int scaleStrip) {
    constexpr int KI = KT / 32;
    constexpr int T = NS * KI;
    constexpr int CPR = KT / 8;
    constexpr int LPR = CPR;
    constexpr int RPC = 64 / LPR;
    constexpr int SW = (CPR < 16) ? CPR - 1 : 15;
    constexpr int ACH = (64 * KT * 2) / 1024;
    constexpr int ACW = ACH / 4;
    constexpr int ABY = 64 * KT * 2;
    constexpr int BPB = 4096;
    __shared__ __align__(16) char lds[ABY + 4 * BPB];

    const int tid = threadIdx.x, lane = tid & 63, w = tid >> 6;
    const int m0 = blockIdx.x * 64;
    const int l15 = lane & 15, lq = lane >> 4;
    const int lr = lane >> 2, lc = lane & 3;

    const char* gA = (const char*)A;
    const char* gBh = (const char*)Bhp;
    const char* gBl = (const char*)Blp;
    const size_t ldaB = (size_t)lda * 2, ldbB = (size_t)ldb * 2;

#pragma unroll
    for (int i = 0; i < ACW; ++i) {
        int c = w * ACW + i;
        int r = c * RPC + lane / LPR;
        int col = lane % LPR;
        int scol = col ^ (r & SW);
        int gv = m0 + r;
        if (gv >= M) gv = M - 1;
        gld16(gA + (size_t)gv * ldaB + scol * 16, lds + c * 1024);
    }

    auto stageB = [&](int ns, int kt, int buf) {
        char* bb = lds + ABY + buf * 2 * BPB;
        int r = w * 16 + lr;
        int sc = (lc ^ (r & 3)) << 4;
        size_t goff = (size_t)(ns * 64 + r) * ldbB + kt * 64 + sc;
        gld16(gBh + goff, bb + w * 1024);
        gld16(gBl + goff, bb + BPB + w * 1024);
    };

    f32x4 acch[4], accl[4];

    auto compute = [&](int buf, int kt) {
        const char* Ab = lds;
        const char* Bhb = lds + ABY + buf * 2 * BPB;
        const char* Blb = Bhb + BPB;
        int ra = w * 16 + l15;
        int cc = kt * 4 + lq;
        f16x8 af = *(const f16x8*)(Ab + ra * (KT * 2) + ((cc ^ (ra & SW)) << 4));
#pragma unroll
        for (int fn = 0; fn < 4; ++fn) {
            int rb = fn * 16 + l15;
            int o = rb * 64 + ((lq ^ (rb & 3)) << 4);
            f16x8 bhv = *(const f16x8*)(Bhb + o);
            f16x8 blv = *(const f16x8*)(Blb + o);
            acch[fn] = __builtin_amdgcn_mfma_f32_16x16x32_f16(af, bhv, acch[fn], 0, 0, 0);
            accl[fn] = __builtin_amdgcn_mfma_f32_16x16x32_f16(af, blv, accl[fn], 0, 0, 0);
        }
    };

    stageB(0, 0, 0);
    int buf = 0;
    for (int t = 0; t < T; ++t) {
        int ns = t / KI, kt = t - ns * KI;
        __syncthreads();
        if (t + 1 < T) {
            int t1 = t + 1;
            stageB(t1 / KI, t1 - (t1 / KI) * KI, buf ^ 1);
        }
        if (kt == 0) {
#pragma unroll
            for (int fn = 0; fn < 4; ++fn) {
                acch[fn] = (f32x4){0.f, 0.f, 0.f, 0.f};
                accl[fn] = (f32x4){0.f, 0.f, 0.f, 0.f};
            }
        }
        compute(buf, kt);
        if (kt == KI - 1) {
#pragma unroll
            for (int fn = 0; fn < 4; ++fn)
#pragma unroll
                for (int i = 0; i < 4; ++i) {
                    int gr = m0 + w * 16 + lq * 4 + i;
                    if (gr >= M) continue;
                    int gc = ns * 64 + fn * 16 + l15;
                    float v = acch[fn][i] + accl[fn][i] * LO_INV;
                    if (ns == scaleStrip) v *= scaleRows[gr];
                    v = epi_apply(v, gc, epi, bias, bng, bnb);
                    if (OUTF32)
                        ((float*)Cp)[(size_t)gr * ldc + gc] = v;
                    else
                        ((half_t*)Cp)[(size_t)gr * ldc + gc] = (half_t)v;
                }
        }
        buf ^= 1;
    }
}

// ---------------- fuse2: MLP2a -> MLP2b (Z2 in LDS, fp32 out) ---------------

__global__ __launch_bounds__(256) void fuse2(
    int M, const half_t* __restrict__ ACC2, const half_t* __restrict__ W1h,
    const half_t* __restrict__ W1l, const half_t* __restrict__ W2h,
    const half_t* __restrict__ W2l, float* __restrict__ outp,
    const float* __restrict__ b1, const float* __restrict__ bg,
    const float* __restrict__ bb, const float* __restrict__ b2) {
    constexpr int BPB = 4096;
    __shared__ __align__(16) char ldsA[8192];
    __shared__ __align__(16) char ldsZ[16384];
    __shared__ __align__(16) char ldsB[4 * BPB];

    const int tid = threadIdx.x, lane = tid & 63, w = tid >> 6;
    const int m0 = blockIdx.x * 64;
    const int l15 = lane & 15, lq = lane >> 4;
    const int lr = lane >> 2, lc = lane & 3;

#pragma unroll
    for (int i = 0; i < 2; ++i) {
        int c = w * 2 + i;
        int r = c * 8 + (lane >> 3);
        int colx = lane & 7;
        int scol = colx ^ (r & 7);
        int gv = m0 + r;
        if (gv >= M) gv = M - 1;
        gld16((const char*)ACC2 + (size_t)gv * 128 + scol * 16, ldsA + c * 1024);
    }

    auto stageB = [&](const char* Bh_, const char* Bl_, size_t ldbB_, int rowoff, int kt,
                      int bufb) {
        char* bbuf = ldsB + bufb * 2 * BPB;
        int r = w * 16 + lr;
        int sc = (lc ^ (r & 3)) << 4;
        size_t goff = (size_t)(rowoff + r) * ldbB_ + (size_t)kt * 64 + sc;
        gld16(Bh_ + goff, bbuf + w * 1024);
        gld16(Bl_ + goff, bbuf + BPB + w * 1024);
    };
    auto stageTile = [&](int t, int bufb) {
        if (t < 4)
            stageB((const char*)W1h, (const char*)W1l, 128, (t >> 1) * 64, t & 1, bufb);
        else
            stageB((const char*)W2h, (const char*)W2l, 256, 0, t - 4, bufb);
    };

    f32x4 acch[4], accl[4];
    auto zacc = [&]() {
#pragma unroll
        for (int fn = 0; fn < 4; ++fn) {
            acch[fn] = (f32x4){0.f, 0.f, 0.f, 0.f};
            accl[fn] = (f32x4){0.f, 0.f, 0.f, 0.f};
        }
    };
    auto computeT = [&](const char* Ab, int astride, int asw, int bufb, int cc0) {
        const char* Bhb = ldsB + bufb * 2 * BPB;
        const char* Blb = Bhb + BPB;
        int ra = w * 16 + l15;
        int cc = cc0 + lq;
        f16x8 af = *(const f16x8*)(Ab + ra * astride + ((cc ^ (ra & asw)) << 4));
#pragma unroll
        for (int fn = 0; fn < 4; ++fn) {
            int rb = fn * 16 + l15;
            int o = rb * 64 + ((lq ^ (rb & 3)) << 4);
            f16x8 bhv = *(const f16x8*)(Bhb + o);
            f16x8 blv = *(const f16x8*)(Blb + o);
            acch[fn] = __builtin_amdgcn_mfma_f32_16x16x32_f16(af, bhv, acch[fn], 0, 0, 0);
            accl[fn] = __builtin_amdgcn_mfma_f32_16x16x32_f16(af, blv, accl[fn], 0, 0, 0);
        }
    };

    stageTile(0, 0);
    int buf = 0;
    for (int t = 0; t < 8; ++t) {
        __syncthreads();
        if (t + 1 < 8) stageTile(t + 1, buf ^ 1);
        if (t < 4) {
            int kt = t & 1, ns = t >> 1;
            if (kt == 0) zacc();
            computeT(ldsA, 128, 7, buf, kt * 4);
            if (kt == 1) {
#pragma unroll
                for (int fn = 0; fn < 4; ++fn)
#pragma unroll
                    for (int i = 0; i < 4; ++i) {
                        int r = w * 16 + lq * 4 + i;
                        int gc = ns * 64 + fn * 16 + l15;
                        float v = acch[fn][i] + accl[fn][i] * LO_INV;
                        v = bg[gc] * ((v + b1[gc]) * BNSCALE) + bb[gc];
                        v = fmaxf(v, 0.f);
                        int ch = (gc >> 3) ^ (r & 15);
                        *(half_t*)(ldsZ + r * 256 + (ch << 4) + (gc & 7) * 2) = (half_t)v;
                    }
            }
        } else {
            int tt = t - 4;
            if (tt == 0) zacc();
            computeT(ldsZ, 256, 15, buf, tt * 4);
            if (tt == 3) {
#pragma unroll
                for (int fn = 0; fn < 4; ++fn)
#pragma unroll
                    for (int i = 0; i < 4; ++i) {
                        int gr = m0 + w * 16 + lq * 4 + i;
                        if (gr >= M) continue;
                        int gc = fn * 16 + l15;
                        float v = acch[fn][i] + accl[fn][i] * LO_INV;
                        outp[(size_t)gr * 64 + gc] = v + b2[gc];
                    }
            }
        }
        buf ^= 1;
    }
}

extern "C" void kernel_launch(void* const* d_in, const int* in_sizes, int n_in,
                              void* d_out, int out_size, void* d_ws, size_t ws_size,
                              hipStream_t stream) {
    const float* x     = (const float*)d_in[0];
    const int*   ei    = (const int*)d_in[1];
    const float* lins1 = (const float*)d_in[2];
    const float* bias1 = (const float*)d_in[3];
    const float* m1w1  = (const float*)d_in[4];
    const float* m1b1  = (const float*)d_in[5];
    const float* bn1g  = (const float*)d_in[6];
    const float* bn1b  = (const float*)d_in[7];
    const float* m1w2  = (const float*)d_in[8];
    const float* m1b2  = (const float*)d_in[9];
    const float* lins2 = (const float*)d_in[10];
    const float* bias2 = (const float*)d_in[11];
    const float* m2w1  = (const float*)d_in[12];
    const float* m2b1  = (const float*)d_in[13];
    const float* bn2g  = (const float*)d_in[14];
    const float* bn2b  = (const float*)d_in[15];
    const float* m2w2  = (const float*)d_in[16];
    const float* m2b2  = (const float*)d_in[17];
    float* out = (float*)d_out;

    const int N = in_sizes[0] / 128;
    const int E = in_sizes[1] / 2;
    const int* row = ei;
    const int* col = ei + E;

    char* ws = (char*)d_ws;
    size_t o = 0;
    auto alloc = [&](size_t bytes) {
        void* p = ws + o;
        o += (bytes + 255) & ~(size_t)255;
        return p;
    };
    int*            deg  = (int*)alloc((size_t)N * 4);
    int*            cur  = (int*)alloc((size_t)N * 4);
    float*          dis  = (float*)alloc((size_t)N * 4);
    float*          sA   = (float*)alloc((size_t)N * 4);
    float*          rsA  = (float*)alloc((size_t)N * 4);
    int*            off  = (int*)alloc((size_t)(N + 1) * 4);
    int*            bsum = (int*)alloc(1024 * 4);
    float*          Trow = (float*)alloc(6 * 64 * 4);
    float*          Tpar = (float*)alloc(48 * 64 * 4);
    unsigned short* esrc = (unsigned short*)alloc((size_t)E * 2);
    half_t* g0    = (half_t*)alloc((size_t)N * 128 * 2);
    half_t* ACC   = (half_t*)alloc((size_t)N * 128 * 2);
    half_t* Z     = (half_t*)alloc((size_t)N * 256 * 2);
    half_t* H1    = (half_t*)alloc((size_t)N * 128 * 2);
    half_t* ACC2  = (half_t*)alloc((size_t)N * 64 * 2);
    half_t* Wc1h  = (half_t*)alloc((size_t)128 * 896 * 2);
    half_t* Wc1l  = (half_t*)alloc((size_t)128 * 896 * 2);
    half_t* Wc2h  = (half_t*)alloc((size_t)448 * 128 * 2);
    half_t* Wc2l  = (half_t*)alloc((size_t)448 * 128 * 2);
    half_t* Wm1ah = (half_t*)alloc((size_t)256 * 128 * 2);
    half_t* Wm1al = (half_t*)alloc((size_t)256 * 128 * 2);
    half_t* Wm1bh = (half_t*)alloc((size_t)128 * 256 * 2);
    half_t* Wm1bl = (half_t*)alloc((size_t)128 * 256 * 2);
    half_t* Wm2ah = (half_t*)alloc((size_t)128 * 64 * 2);
    half_t* Wm2al = (half_t*)alloc((size_t)128 * 64 * 2);
    half_t* Wm2bh = (half_t*)alloc((size_t)64 * 128 * 2);
    half_t* Wm2bl = (half_t*)alloc((size_t)64 * 128 * 2);
    half_t* slab  = (half_t*)alloc((size_t)N * 896 * 2);
    (void)ws_size;

    const int TPB = 256;
    const int nb = (N + 1023) / 1024;
    zero2_i32<<<(N + TPB - 1) / TPB, TPB, 0, stream>>>(deg, cur, N);
    count_deg<<<(E + TPB - 1) / TPB, TPB, 0, stream>>>(col, deg, E);
    compute_dis_s<<<(N + TPB - 1) / TPB, TPB, 0, stream>>>(deg, dis, sA, rsA, N);
    scan_blk<<<nb, 1024, 0, stream>>>(deg, off, bsum, N);
    scan_top<<<1, 64, 0, stream>>>(bsum, nb);
    scan_add<<<nb, 1024, 0, stream>>>(off, bsum, N);
    fill_edges<<<(E + TPB - 1) / TPB, TPB, 0, stream>>>(row, col, off, cur, esrc, E);
    conv_all<<<(253952 + TPB - 1) / TPB, TPB, 0, stream>>>(
        lins1, lins2, m1w1, m1w2, m2w1, m2w2, Wc1h, Wc1l, Wc2h, Wc2l, Wm1ah, Wm1al, Wm1bh,
        Wm1bl, Wm2ah, Wm2al, Wm2bh, Wm2bl);
    trows_part<<<48, 256, 0, stream>>>(lins2, Tpar);
    trows_final<<<1, 384, 0, stream>>>(Tpar, Trow);
    conv_xg<<<(N * 128 + TPB - 1) / TPB, TPB, 0, stream>>>(x, slab, g0, dis, sA, N * 128);

    unsigned* slabU = (unsigned*)slab;
    unsigned* g0U = (unsigned*)g0;
    const int HG = (N + 63) / 64;
    const int HG128 = (N + 127) / 128;

    // ---- Layer 1: 6 hops in ONE cooperative kernel, then concat GEMM ----
    {
        const unsigned* a0 = g0U;
        unsigned* a1 = slabU;
        const float* a2 = dis;
        const int* a3 = off;
        const unsigned short* a4 = esrc;
        int a5 = N;
        void* args[] = {&a0, &a1, &a2, &a3, &a4, &a5};
        hipLaunchCooperativeKernel((void*)prop6, dim3(1024), dim3(256), args, 0, stream);
    }
    gemmc<<<HG128, 512, 0, stream>>>(N, 28, slab, 896, Wc1h, Wc1l, 896, ACC, 128, rsA, bias1);

    // ---- MLP1 + P-GEMM (separate gemmn kernels; fuse1 reverted) ----
    gemmn<128, 4, 0><<<HG, 256, 0, stream>>>(
        N, ACC, 128, Wm1ah, Wm1al, 128, Z, 256, 2, m1b1, bn1g, bn1b, nullptr, -1);
    gemmn<256, 2, 0><<<HG, 256, 0, stream>>>(
        N, Z, 256, Wm1bh, Wm1bl, 256, H1, 128, 3, m1b2, nullptr, nullptr, nullptr, -1);
    gemmn<128, 7, 0><<<HG, 256, 0, stream>>>(
        N, H1, 128, Wc2h, Wc2l, 128, slab, 448, 0, nullptr, nullptr, nullptr, dis, 6);

    // ---- Layer 2 Horner: 6 steps in ONE cooperative kernel ----
    {
        const half_t* a0 = slab;
        half_t* a1 = g0;
        half_t* a2 = g0 + (size_t)N * 64;
        half_t* a3 = ACC2;
        const float* a4 = dis;
        const int* a5 = off;
        const unsigned short* a6 = esrc;
        const float* a7 = Trow;
        const float* a8 = bias2;
        int a9 = N;
        void* args[] = {&a0, &a1, &a2, &a3, &a4, &a5, &a6, &a7, &a8, &a9};
        hipLaunchCooperativeKernel((void*)horner6, dim3(1024), dim3(256), args, 0, stream);
    }

    // ---- fused MLP2: ACC2 -> out ----
    fuse2<<<HG, 256, 0, stream>>>(N, ACC2, Wm2ah, Wm2al, Wm2bh, Wm2bl, out, m2b1, bn2g, bn2b,
                                  m2b2);
}

// Round 19
// 673.321 us; speedup vs baseline: 2.9580x; 2.9580x over previous
//
#include <hip/hip_runtime.h>
#include <hip/hip_bf16.h>

// TAGConv x2 GNN on MI355X. v19 = v16 (best measured, 673us), restored after
// the cooperative-kernel experiment (v18) regressed 3x (grid.sync serializes
// the chip; persistent grid destroyed gather pipelining).
//  - props: wave-per-node 8-deep gathers, separate launches (BW-floored at
//    ~2.3 TB/s random-gather; depth/split/bucket/coop all falsified).
//  - layer 1: 6 props @128ch -> slab [N,896] of dis*h_k; concat-K=896 GEMM
//    (BM=128 x BK=32, 512 thr) with rs=sqrt(deg) recovery epilogue.
//  - layer 2: weight-commuted Horner (P = h1@[W2_0..W2_6]), 6 props @64ch.
//  - gemmn: A staged once in LDS, loop over BN=64 strips, B double-buffered.
//  - single-pass fill_edges, 2-stage trows reduce.

#define EPS_MSG 1e-7f
#define BNSCALE 0.9999950000374997f  // 1/sqrt(1+1e-5)
#define LO_INV 0.0009765625f         // 2^-10

typedef _Float16 half_t;
typedef _Float16 f16x8 __attribute__((ext_vector_type(8)));
typedef float f32x4 __attribute__((ext_vector_type(4)));

__device__ __forceinline__ void gld16(const char* g, char* l) {
    __builtin_amdgcn_global_load_lds(
        (const __attribute__((address_space(1))) void*)g,
        (__attribute__((address_space(3))) void*)l, 16, 0, 0);
}

__device__ __forceinline__ float hlo(unsigned p) {
    unsigned short u = (unsigned short)(p & 0xffffu);
    half_t h;
    __builtin_memcpy(&h, &u, 2);
    return (float)h;
}
__device__ __forceinline__ float hhi(unsigned p) {
    unsigned short u = (unsigned short)(p >> 16);
    half_t h;
    __builtin_memcpy(&h, &u, 2);
    return (float)h;
}
__device__ __forceinline__ unsigned fpack2(float x, float y) {
    half_t a = (half_t)x, b = (half_t)y;
    unsigned short ua, ub;
    __builtin_memcpy(&ua, &a, 2);
    __builtin_memcpy(&ub, &b, 2);
    return (unsigned)ua | ((unsigned)ub << 16);
}

__device__ __forceinline__ float epi_apply(float v, int gc, int epi,
                                           const float* __restrict__ bias,
                                           const float* __restrict__ bng,
                                           const float* __restrict__ bnb) {
    if (epi == 1) {
        v += bias[gc];
    } else if (epi == 2) {
        v = bng[gc] * ((v + bias[gc]) * BNSCALE) + bnb[gc];
        v = fmaxf(v, 0.f);
    } else if (epi == 3) {
        v = fmaxf(v + bias[gc], 0.f);
    }
    return v;
}

// ---------------- CSR build ----------------

__global__ void zero2_i32(int* __restrict__ a, int* __restrict__ b, int n) {
    int i = blockIdx.x * blockDim.x + threadIdx.x;
    if (i < n) {
        a[i] = 0;
        b[i] = 0;
    }
}

__global__ void count_deg(const int* __restrict__ col, int* __restrict__ deg, int E) {
    int e = blockIdx.x * blockDim.x + threadIdx.x;
    if (e < E) atomicAdd(&deg[col[e]], 1);
}

__global__ void compute_dis_s(const int* __restrict__ deg, float* __restrict__ dis,
                              float* __restrict__ s, float* __restrict__ rs, int N) {
    int v = blockIdx.x * blockDim.x + threadIdx.x;
    if (v >= N) return;
    int d = deg[v];
    float di = (d > 0) ? rsqrtf((float)d) : 0.f;
    dis[v] = di;
    s[v] = (d > 0) ? di : 1.f;
    rs[v] = (d > 0) ? sqrtf((float)d) : 1.f;
}

__global__ void scan_blk(const int* __restrict__ deg, int* __restrict__ off,
                         int* __restrict__ bsum, int N) {
    __shared__ int sm[1024];
    int i = blockIdx.x * 1024 + threadIdx.x;
    sm[threadIdx.x] = (i < N) ? deg[i] : 0;
    __syncthreads();
    for (int ofs = 1; ofs < 1024; ofs <<= 1) {
        int t = (threadIdx.x >= (unsigned)ofs) ? sm[threadIdx.x - ofs] : 0;
        __syncthreads();
        sm[threadIdx.x] += t;
        __syncthreads();
    }
    if (i < N) off[i + 1] = sm[threadIdx.x];
    if (threadIdx.x == 0) bsum[blockIdx.x] = sm[1023];
}

__global__ void scan_top(int* __restrict__ bsum, int nb) {
    if (threadIdx.x == 0 && blockIdx.x == 0) {
        int a = 0;
        for (int b = 0; b < nb; ++b) {
            int t = bsum[b];
            bsum[b] = a;
            a += t;
        }
    }
}

__global__ void scan_add(int* __restrict__ off, const int* __restrict__ bsum, int N) {
    int i = blockIdx.x * 1024 + threadIdx.x;
    if (i < N) off[i + 1] += bsum[blockIdx.x];
    if (i == 0) off[0] = 0;
}

__global__ void fill_edges(const int* __restrict__ row, const int* __restrict__ col,
                           const int* __restrict__ off, int* __restrict__ cur,
                           unsigned short* __restrict__ esrc, int E) {
    int e = blockIdx.x * blockDim.x + threadIdx.x;
    if (e >= E) return;
    int c = col[e];
    int pos = off[c] + atomicAdd(&cur[c], 1);
    esrc[pos] = (unsigned short)row[e];
}

// ---------------- conversions ----------------

__global__ void conv_xg(const float* __restrict__ x, half_t* __restrict__ slab,
                        half_t* __restrict__ g0, const float* __restrict__ dis,
                        const float* __restrict__ s, int total) {
    int i = blockIdx.x * blockDim.x + threadIdx.x;
    if (i >= total) return;
    int v = i >> 7, c = i & 127;
    float xv = x[i];
    slab[(size_t)v * 896 + c] = (half_t)(s[v] * xv);
    g0[i] = (half_t)(dis[v] * fmaxf(xv, 0.f));
}

__device__ __forceinline__ void wcv(const float* __restrict__ in, half_t* __restrict__ oh,
                                    half_t* __restrict__ ol, int nm, int K, int Nn, int i) {
    int KT = nm * K;
    int n = i / KT;
    int rem = i - n * KT;
    int km = rem / K, k = rem - km * K;
    float w = in[(size_t)km * K * Nn + (size_t)k * Nn + n];
    half_t h = (half_t)w;
    oh[i] = h;
    ol[i] = (half_t)((w - (float)h) * 1024.f);
}

__global__ void conv_all(const float* l1, const float* l2, const float* a1, const float* b1,
                         const float* a2, const float* b2, half_t* W1h, half_t* W1l,
                         half_t* W2h, half_t* W2l, half_t* M1ah, half_t* M1al, half_t* M1bh,
                         half_t* M1bl, half_t* M2ah, half_t* M2al, half_t* M2bh,
                         half_t* M2bl) {
    int i = blockIdx.x * blockDim.x + threadIdx.x;
    if (i < 114688) {
        wcv(l1, W1h, W1l, 7, 128, 128, i);  // concat-K layout for layer-1
    } else if (i < 172032) {
        // W2: concat-N layout. B^T[np][k], np = km*64+n, value = l2[km][k][n]
        int j = i - 114688;
        int np = j >> 7, k = j & 127;
        int km = np >> 6, n = np & 63;
        float w = l2[(size_t)km * 128 * 64 + (size_t)k * 64 + n];
        half_t h = (half_t)w;
        W2h[j] = h;
        W2l[j] = (half_t)((w - (float)h) * 1024.f);
    } else if (i < 204800) {
        wcv(a1, M1ah, M1al, 1, 128, 256, i - 172032);
    } else if (i < 237568) {
        wcv(b1, M1bh, M1bl, 1, 256, 128, i - 204800);
    } else if (i < 245760) {
        wcv(a2, M2ah, M2al, 1, 64, 128, i - 237568);
    } else if (i < 253952) {
        wcv(b2, M2bh, M2bl, 1, 128, 64, i - 245760);
    }
}

// stage A: partial[k-1][p][c] = sum over 16 kk rows
__global__ void trows_part(const float* __restrict__ l2, float* __restrict__ partial) {
    __shared__ float sm[256];
    int k = blockIdx.x / 8 + 1;
    int p = blockIdx.x % 8;
    int c = threadIdx.x & 63;
    int q = threadIdx.x >> 6;
    float a = 0.f;
    int kk0 = p * 16 + q * 4;
#pragma unroll
    for (int t = 0; t < 4; ++t)
        a += l2[(size_t)k * 128 * 64 + (kk0 + t) * 64 + c];
    sm[threadIdx.x] = a;
    __syncthreads();
    if (q == 0)
        partial[(size_t)blockIdx.x * 64 + c] =
            (sm[c] + sm[64 + c]) + (sm[128 + c] + sm[192 + c]);
}

__global__ void trows_final(const float* __restrict__ partial, float* __restrict__ T) {
    int j = threadIdx.x >> 6;
    int c = threadIdx.x & 63;
    if (j >= 6) return;
    float a = 0.f;
    for (int k = j + 1; k <= 6; ++k)
#pragma unroll
        for (int p = 0; p < 8; ++p) a += partial[(size_t)((k - 1) * 8 + p) * 64 + c];
    T[j * 64 + c] = a;
}

// ---------------- propagation, 128ch (layer 1), 8-deep ----------------

__global__ void __launch_bounds__(256) prop(const unsigned* __restrict__ gin, int idl,
                                            unsigned* __restrict__ gout, int odl,
                                            const float* __restrict__ dis,
                                            const int* __restrict__ off,
                                            const unsigned short* __restrict__ esrc, int N) {
    const int lane = threadIdx.x & 63;
    const int w = threadIdx.x >> 6;
    const int stride = gridDim.x * 4;
    for (int v = blockIdx.x * 4 + w; v < N; v += stride) {
        int s = off[v], e = off[v + 1];
        float2 A0 = {0.f, 0.f}, A1 = {0.f, 0.f}, A2 = {0.f, 0.f}, A3 = {0.f, 0.f};
        float2 A4 = {0.f, 0.f}, A5 = {0.f, 0.f}, A6 = {0.f, 0.f}, A7 = {0.f, 0.f};
        for (int i = s; i < e; i += 8) {
            unsigned p[8];
            int ok[8];
#pragma unroll
            for (int j = 0; j < 8; ++j) {
                int ij = i + j;
                ok[j] = ij < e;
                int idx = ok[j] ? ij : e - 1;
                p[j] = gin[esrc[idx] * idl + lane];
            }
            A0.x += ok[0] ? hlo(p[0]) : 0.f; A0.y += ok[0] ? hhi(p[0]) : 0.f;
            A1.x += ok[1] ? hlo(p[1]) : 0.f; A1.y += ok[1] ? hhi(p[1]) : 0.f;
            A2.x += ok[2] ? hlo(p[2]) : 0.f; A2.y += ok[2] ? hhi(p[2]) : 0.f;
            A3.x += ok[3] ? hlo(p[3]) : 0.f; A3.y += ok[3] ? hhi(p[3]) : 0.f;
            A4.x += ok[4] ? hlo(p[4]) : 0.f; A4.y += ok[4] ? hhi(p[4]) : 0.f;
            A5.x += ok[5] ? hlo(p[5]) : 0.f; A5.y += ok[5] ? hhi(p[5]) : 0.f;
            A6.x += ok[6] ? hlo(p[6]) : 0.f; A6.y += ok[6] ? hhi(p[6]) : 0.f;
            A7.x += ok[7] ? hlo(p[7]) : 0.f; A7.y += ok[7] ? hhi(p[7]) : 0.f;
        }
        float ax = ((A0.x + A1.x) + (A2.x + A3.x)) + ((A4.x + A5.x) + (A6.x + A7.x));
        float ay = ((A0.y + A1.y) + (A2.y + A3.y)) + ((A4.y + A5.y) + (A6.y + A7.y));
        float dv = dis[v];
        float ce = (float)(e - s) * EPS_MSG;
        float hx = fmaf(dv, ax, ce);
        float hy = fmaf(dv, ay, ce);
        gout[v * odl + lane] = fpack2(dv * hx, dv * hy);
    }
}

// ---------------- propagation, 64ch Horner step (layer 2), 8-deep ----------

template <int FINAL>
__global__ void __launch_bounds__(256) prop64(
    const half_t* __restrict__ uin, int ldu, const half_t* __restrict__ pj, int ldp,
    half_t* __restrict__ uout, int ldo, const float* __restrict__ dis,
    const int* __restrict__ off, const unsigned short* __restrict__ esrc,
    const float* __restrict__ tj, const float* __restrict__ bias2, int N) {
    const int c = threadIdx.x & 63;
    const int w = threadIdx.x >> 6;
    const int stride = gridDim.x * 4;
    for (int v = blockIdx.x * 4 + w; v < N; v += stride) {
        int s = off[v], e = off[v + 1];
        float a0 = 0.f, a1 = 0.f, a2 = 0.f, a3 = 0.f;
        float a4 = 0.f, a5 = 0.f, a6 = 0.f, a7 = 0.f;
        for (int i = s; i < e; i += 8) {
            float q[8];
            int ok[8];
#pragma unroll
            for (int j = 0; j < 8; ++j) {
                int ij = i + j;
                ok[j] = ij < e;
                int idx = ok[j] ? ij : e - 1;
                q[j] = (float)uin[(size_t)esrc[idx] * ldu + c];
            }
            a0 += ok[0] ? q[0] : 0.f;
            a1 += ok[1] ? q[1] : 0.f;
            a2 += ok[2] ? q[2] : 0.f;
            a3 += ok[3] ? q[3] : 0.f;
            a4 += ok[4] ? q[4] : 0.f;
            a5 += ok[5] ? q[5] : 0.f;
            a6 += ok[6] ? q[6] : 0.f;
            a7 += ok[7] ? q[7] : 0.f;
        }
        float acc = ((a0 + a1) + (a2 + a3)) + ((a4 + a5) + (a6 + a7));
        float dv = dis[v];
        float base = (float)pj[(size_t)v * ldp + c] + (float)(e - s) * EPS_MSG * tj[c];
        float u = fmaf(dv, acc, base);
        if (FINAL)
            uout[(size_t)v * ldo + c] = (half_t)(u + bias2[c]);
        else
            uout[(size_t)v * ldo + c] = (half_t)(dv * u);
    }
}

// ---------------- concat GEMM: BM=128, BN=128, BK=32, 512 thr, dbuf ---------

__global__ __launch_bounds__(512) void gemmc(
    int M, int kiters, const half_t* __restrict__ A, int lda,
    const half_t* __restrict__ Bhp, const half_t* __restrict__ Blp, int ldb,
    half_t* __restrict__ Cp, int ldc, const float* __restrict__ rs,
    const float* __restrict__ bias) {
    constexpr int ABY = 8192, BBY = 8192, BUFBY = ABY + 2 * BBY;  // 24576
    __shared__ __align__(16) char lds[2][BUFBY];

    const int tid = threadIdx.x, lane = tid & 63, w = tid >> 6;  // 8 waves
    const int wr = w >> 1, wc = w & 1;
    const int m0 = blockIdx.x * 128;
    const int l15 = lane & 15, lq = lane >> 4;
    const int lr = lane >> 2, lc = lane & 3;

    const char* gA = (const char*)A;
    const char* gBh = (const char*)Bhp;
    const char* gBl = (const char*)Blp;
    const size_t ldaB = (size_t)lda * 2, ldbB = (size_t)ldb * 2;

    auto stage = [&](int kt, int buf) {
        const int k0b = kt * 64;
        char* base = lds[0] + buf * BUFBY;
        int r = w * 16 + lr;
        int sc = (lc ^ (r & 3)) << 4;
        {
            int gv = m0 + r;
            if (gv >= M) gv = M - 1;
            gld16(gA + (size_t)gv * ldaB + k0b + sc, base + w * 1024);
        }
        {
            size_t goff = (size_t)r * ldbB + k0b + sc;
            gld16(gBh + goff, base + ABY + w * 1024);
            gld16(gBl + goff, base + ABY + BBY + w * 1024);
        }
    };

    f32x4 acch[2][4], accl[2][4];
#pragma unroll
    for (int fm = 0; fm < 2; ++fm)
#pragma unroll
        for (int fn = 0; fn < 4; ++fn) {
            acch[fm][fn] = (f32x4){0.f, 0.f, 0.f, 0.f};
            accl[fm][fn] = (f32x4){0.f, 0.f, 0.f, 0.f};
        }

    auto compute = [&](int buf) {
        const char* Ab = lds[0] + buf * BUFBY;
        const char* Bhb = Ab + ABY;
        const char* Blb = Ab + ABY + BBY;
        f16x8 af[2];
#pragma unroll
        for (int fm = 0; fm < 2; ++fm) {
            int ra = wr * 32 + fm * 16 + l15;
            af[fm] = *(const f16x8*)(Ab + ra * 64 + ((lq ^ (ra & 3)) << 4));
        }
#pragma unroll
        for (int fn = 0; fn < 4; ++fn) {
            int rb = wc * 64 + fn * 16 + l15;
            int o = rb * 64 + ((lq ^ (rb & 3)) << 4);
            f16x8 bhv = *(const f16x8*)(Bhb + o);
            f16x8 blv = *(const f16x8*)(Blb + o);
#pragma unroll
            for (int fm = 0; fm < 2; ++fm) {
                acch[fm][fn] = __builtin_amdgcn_mfma_f32_16x16x32_f16(af[fm], bhv, acch[fm][fn], 0, 0, 0);
                accl[fm][fn] = __builtin_amdgcn_mfma_f32_16x16x32_f16(af[fm], blv, accl[fm][fn], 0, 0, 0);
            }
        }
    };

    stage(0, 0);
    int buf = 0;
    for (int kt = 0; kt < kiters; ++kt) {
        __syncthreads();
        if (kt + 1 < kiters) stage(kt + 1, buf ^ 1);
        compute(buf);
        buf ^= 1;
    }

#pragma unroll
    for (int fm = 0; fm < 2; ++fm)
#pragma unroll
        for (int fn = 0; fn < 4; ++fn)
#pragma unroll
            for (int i = 0; i < 4; ++i) {
                int gr = m0 + wr * 32 + fm * 16 + lq * 4 + i;
                if (gr >= M) continue;
                int gc = wc * 64 + fn * 16 + l15;
                float v = acch[fm][fn][i] + accl[fm][fn][i] * LO_INV;
                v = v * rs[gr] + bias[gc];
                Cp[(size_t)gr * ldc + gc] = (half_t)v;
            }
}

// ---------------- loop-N GEMM: A staged once, B dbuf per strip-tile ----------

template <int KT, int NS, int OUTF32>
__global__ __launch_bounds__(256) void gemmn(
    int M, const half_t* __restrict__ A, int lda, const half_t* __restrict__ Bhp,
    const half_t* __restrict__ Blp, int ldb, void* __restrict__ Cp, int ldc, int epi,
    const float* __restrict__ bias, const float* __restrict__ bng,
    const float* __restrict__ bnb, const float* __restrict__ scaleRows, int scaleStrip) {
    constexpr int KI = KT / 32;
    constexpr int T = NS * KI;
    constexpr int CPR = KT / 8;
    constexpr int LPR = CPR;
    constexpr int RPC = 64 / LPR;
    constexpr int SW = (CPR < 16) ? CPR - 1 : 15;
    constexpr int ACH = (64 * KT * 2) / 1024;
    constexpr int ACW = ACH / 4;
    constexpr int ABY = 64 * KT * 2;
    constexpr int BPB = 4096;
    __shared__ __align__(16) char lds[ABY + 4 * BPB];

    const int tid = threadIdx.x, lane = tid & 63, w = tid >> 6;
    const int m0 = blockIdx.x * 64;
    const int l15 = lane & 15, lq = lane >> 4;
    const int lr = lane >> 2, lc = lane & 3;

    const char* gA = (const char*)A;
    const char* gBh = (const char*)Bhp;
    const char* gBl = (const char*)Blp;
    const size_t ldaB = (size_t)lda * 2, ldbB = (size_t)ldb * 2;

#pragma unroll
    for (int i = 0; i < ACW; ++i) {
        int c = w * ACW + i;
        int r = c * RPC + lane / LPR;
        int col = lane % LPR;
        int scol = col ^ (r & SW);
        int gv = m0 + r;
        if (gv >= M) gv = M - 1;
        gld16(gA + (size_t)gv * ldaB + scol * 16, lds + c * 1024);
    }

    auto stageB = [&](int ns, int kt, int buf) {
        char* bb = lds + ABY + buf * 2 * BPB;
        int r = w * 16 + lr;
        int sc = (lc ^ (r & 3)) << 4;
        size_t goff = (size_t)(ns * 64 + r) * ldbB + kt * 64 + sc;
        gld16(gBh + goff, bb + w * 1024);
        gld16(gBl + goff, bb + BPB + w * 1024);
    };

    f32x4 acch[4], accl[4];

    auto compute = [&](int buf, int kt) {
        const char* Ab = lds;
        const char* Bhb = lds + ABY + buf * 2 * BPB;
        const char* Blb = Bhb + BPB;
        int ra = w * 16 + l15;
        int cc = kt * 4 + lq;
        f16x8 af = *(const f16x8*)(Ab + ra * (KT * 2) + ((cc ^ (ra & SW)) << 4));
#pragma unroll
        for (int fn = 0; fn < 4; ++fn) {
            int rb = fn * 16 + l15;
            int o = rb * 64 + ((lq ^ (rb & 3)) << 4);
            f16x8 bhv = *(const f16x8*)(Bhb + o);
            f16x8 blv = *(const f16x8*)(Blb + o);
            acch[fn] = __builtin_amdgcn_mfma_f32_16x16x32_f16(af, bhv, acch[fn], 0, 0, 0);
            accl[fn] = __builtin_amdgcn_mfma_f32_16x16x32_f16(af, blv, accl[fn], 0, 0, 0);
        }
    };

    stageB(0, 0, 0);
    int buf = 0;
    for (int t = 0; t < T; ++t) {
        int ns = t / KI, kt = t - ns * KI;
        __syncthreads();
        if (t + 1 < T) {
            int t1 = t + 1;
            stageB(t1 / KI, t1 - (t1 / KI) * KI, buf ^ 1);
        }
        if (kt == 0) {
#pragma unroll
            for (int fn = 0; fn < 4; ++fn) {
                acch[fn] = (f32x4){0.f, 0.f, 0.f, 0.f};
                accl[fn] = (f32x4){0.f, 0.f, 0.f, 0.f};
            }
        }
        compute(buf, kt);
        if (kt == KI - 1) {
#pragma unroll
            for (int fn = 0; fn < 4; ++fn)
#pragma unroll
                for (int i = 0; i < 4; ++i) {
                    int gr = m0 + w * 16 + lq * 4 + i;
                    if (gr >= M) continue;
                    int gc = ns * 64 + fn * 16 + l15;
                    float v = acch[fn][i] + accl[fn][i] * LO_INV;
                    if (ns == scaleStrip) v *= scaleRows[gr];
                    v = epi_apply(v, gc, epi, bias, bng, bnb);
                    if (OUTF32)
                        ((float*)Cp)[(size_t)gr * ldc + gc] = v;
                    else
                        ((half_t*)Cp)[(size_t)gr * ldc + gc] = (half_t)v;
                }
        }
        buf ^= 1;
    }
}

extern "C" void kernel_launch(void* const* d_in, const int* in_sizes, int n_in,
                              void* d_out, int out_size, void* d_ws, size_t ws_size,
                              hipStream_t stream) {
    const float* x     = (const float*)d_in[0];
    const int*   ei    = (const int*)d_in[1];
    const float* lins1 = (const float*)d_in[2];
    const float* bias1 = (const float*)d_in[3];
    const float* m1w1  = (const float*)d_in[4];
    const float* m1b1  = (const float*)d_in[5];
    const float* bn1g  = (const float*)d_in[6];
    const float* bn1b  = (const float*)d_in[7];
    const float* m1w2  = (const float*)d_in[8];
    const float* m1b2  = (const float*)d_in[9];
    const float* lins2 = (const float*)d_in[10];
    const float* bias2 = (const float*)d_in[11];
    const float* m2w1  = (const float*)d_in[12];
    const float* m2b1  = (const float*)d_in[13];
    const float* bn2g  = (const float*)d_in[14];
    const float* bn2b  = (const float*)d_in[15];
    const float* m2w2  = (const float*)d_in[16];
    const float* m2b2  = (const float*)d_in[17];
    float* out = (float*)d_out;

    const int N = in_sizes[0] / 128;
    const int E = in_sizes[1] / 2;
    const int* row = ei;
    const int* col = ei + E;

    char* ws = (char*)d_ws;
    size_t o = 0;
    auto alloc = [&](size_t bytes) {
        void* p = ws + o;
        o += (bytes + 255) & ~(size_t)255;
        return p;
    };
    int*            deg  = (int*)alloc((size_t)N * 4);
    int*            cur  = (int*)alloc((size_t)N * 4);
    float*          dis  = (float*)alloc((size_t)N * 4);
    float*          sA   = (float*)alloc((size_t)N * 4);
    float*          rsA  = (float*)alloc((size_t)N * 4);
    int*            off  = (int*)alloc((size_t)(N + 1) * 4);
    int*            bsum = (int*)alloc(1024 * 4);
    float*          Trow = (float*)alloc(6 * 64 * 4);
    float*          Tpar = (float*)alloc(48 * 64 * 4);
    unsigned short* esrc = (unsigned short*)alloc((size_t)E * 2);
    half_t* g0    = (half_t*)alloc((size_t)N * 128 * 2);
    half_t* ACC   = (half_t*)alloc((size_t)N * 128 * 2);
    half_t* Z     = (half_t*)alloc((size_t)N * 256 * 2);
    half_t* H1    = (half_t*)alloc((size_t)N * 128 * 2);
    half_t* ACC2  = (half_t*)alloc((size_t)N * 64 * 2);
    half_t* Wc1h  = (half_t*)alloc((size_t)128 * 896 * 2);
    half_t* Wc1l  = (half_t*)alloc((size_t)128 * 896 * 2);
    half_t* Wc2h  = (half_t*)alloc((size_t)448 * 128 * 2);
    half_t* Wc2l  = (half_t*)alloc((size_t)448 * 128 * 2);
    half_t* Wm1ah = (half_t*)alloc((size_t)256 * 128 * 2);
    half_t* Wm1al = (half_t*)alloc((size_t)256 * 128 * 2);
    half_t* Wm1bh = (half_t*)alloc((size_t)128 * 256 * 2);
    half_t* Wm1bl = (half_t*)alloc((size_t)128 * 256 * 2);
    half_t* Wm2ah = (half_t*)alloc((size_t)128 * 64 * 2);
    half_t* Wm2al = (half_t*)alloc((size_t)128 * 64 * 2);
    half_t* Wm2bh = (half_t*)alloc((size_t)64 * 128 * 2);
    half_t* Wm2bl = (half_t*)alloc((size_t)64 * 128 * 2);
    half_t* slab  = (half_t*)alloc((size_t)N * 896 * 2);
    (void)ws_size;

    const int TPB = 256;
    const int nb = (N + 1023) / 1024;
    zero2_i32<<<(N + TPB - 1) / TPB, TPB, 0, stream>>>(deg, cur, N);
    count_deg<<<(E + TPB - 1) / TPB, TPB, 0, stream>>>(col, deg, E);
    compute_dis_s<<<(N + TPB - 1) / TPB, TPB, 0, stream>>>(deg, dis, sA, rsA, N);
    scan_blk<<<nb, 1024, 0, stream>>>(deg, off, bsum, N);
    scan_top<<<1, 64, 0, stream>>>(bsum, nb);
    scan_add<<<nb, 1024, 0, stream>>>(off, bsum, N);
    fill_edges<<<(E + TPB - 1) / TPB, TPB, 0, stream>>>(row, col, off, cur, esrc, E);
    conv_all<<<(253952 + TPB - 1) / TPB, TPB, 0, stream>>>(
        lins1, lins2, m1w1, m1w2, m2w1, m2w2, Wc1h, Wc1l, Wc2h, Wc2l, Wm1ah, Wm1al, Wm1bh,
        Wm1bl, Wm2ah, Wm2al, Wm2bh, Wm2bl);
    trows_part<<<48, 256, 0, stream>>>(lins2, Tpar);
    trows_final<<<1, 384, 0, stream>>>(Tpar, Trow);
    conv_xg<<<(N * 128 + TPB - 1) / TPB, TPB, 0, stream>>>(x, slab, g0, dis, sA, N * 128);

    unsigned* slabU = (unsigned*)slab;
    unsigned* g0U = (unsigned*)g0;
    const int HG = (N + 63) / 64;
    const int HG128 = (N + 127) / 128;

    // ---- Layer 1: 6 props @128ch into slab cols 1..6, concat-K GEMM ----
    prop<<<2048, 256, 0, stream>>>(g0U, 64, slabU + 64, 448, dis, off, esrc, N);
    for (int k = 2; k <= 6; ++k)
        prop<<<2048, 256, 0, stream>>>(slabU + (size_t)(k - 1) * 64, 448,
                                       slabU + (size_t)k * 64, 448, dis, off, esrc, N);
    gemmc<<<HG128, 512, 0, stream>>>(N, 28, slab, 896, Wc1h, Wc1l, 896, ACC, 128, rsA, bias1);
    // MLP1: Z = relu(bn(ACC@W+b)); h1 = relu(Z@W+b) -> H1
    gemmn<128, 4, 0><<<HG, 256, 0, stream>>>(
        N, ACC, 128, Wm1ah, Wm1al, 128, Z, 256, 2, m1b1, bn1g, bn1b, nullptr, -1);
    gemmn<256, 2, 0><<<HG, 256, 0, stream>>>(
        N, Z, 256, Wm1bh, Wm1bl, 256, H1, 128, 3, m1b2, nullptr, nullptr, nullptr, -1);

    // ---- Layer 2: P = H1 @ [W2_0..W2_6] (concat-N); strip 6 pre-scaled by dis ----
    gemmn<128, 7, 0><<<HG, 256, 0, stream>>>(
        N, H1, 128, Wc2h, Wc2l, 128, slab, 448, 0, nullptr, nullptr, nullptr, dis, 6);

    // ---- Horner: u <- p_j + EPS*indeg*t_j + M u, 6 steps @64ch ----
    half_t* ub0 = g0;
    half_t* ub1 = g0 + (size_t)N * 64;
    prop64<0><<<2048, 256, 0, stream>>>(slab + 384, 448, slab + 320, 448, ub0, 64, dis, off,
                                        esrc, Trow + 5 * 64, nullptr, N);
    prop64<0><<<2048, 256, 0, stream>>>(ub0, 64, slab + 256, 448, ub1, 64, dis, off, esrc,
                                        Trow + 4 * 64, nullptr, N);
    prop64<0><<<2048, 256, 0, stream>>>(ub1, 64, slab + 192, 448, ub0, 64, dis, off, esrc,
                                        Trow + 3 * 64, nullptr, N);
    prop64<0><<<2048, 256, 0, stream>>>(ub0, 64, slab + 128, 448, ub1, 64, dis, off, esrc,
                                        Trow + 2 * 64, nullptr, N);
    prop64<0><<<2048, 256, 0, stream>>>(ub1, 64, slab + 64, 448, ub0, 64, dis, off, esrc,
                                        Trow + 1 * 64, nullptr, N);
    prop64<1><<<2048, 256, 0, stream>>>(ub0, 64, slab, 448, ACC2, 64, dis, off, esrc,
                                        Trow + 0 * 64, bias2, N);

    // ---- MLP2 ----
    gemmn<64, 2, 0><<<HG, 256, 0, stream>>>(
        N, ACC2, 64, Wm2ah, Wm2al, 64, Z, 128, 2, m2b1, bn2g, bn2b, nullptr, -1);
    gemmn<128, 1, 1><<<HG, 256, 0, stream>>>(
        N, Z, 128, Wm2bh, Wm2bl, 128, out, 64, 1, m2b2, nullptr, nullptr, nullptr, -1);
}